// Round 4
// baseline (346.911 us; speedup 1.0000x reference)
//
#include <hip/hip_runtime.h>
#include <hip/hip_bf16.h>

// GemmRS: out[m,n] = sum_{w,k} A[w,m,k]*B[w,n,k]
// A: [8,8192,512] f32, B: [8,1024,512] f32, out: [8192,1024] f32.
//
// R1: dbuf LDS (1 barrier/K-step), bijective XCD swizzle, setprio.
// R2: 128x128 tile -> cvt ~38us + gemm ~63us (staging-throughput bound).
// R3: reg-staged fused cvt FAILED (169us): compiler refused 200+ live regs
//     across the barrier (VGPR=116 -> spill/load-sinking serialization).
//     Lesson: glds (no dest regs) is the only robust bulk-staging path.
// R4: revert to R2 split; B-operand bypasses LDS entirely. B-frag for
//     mfma_16x16x32 is 16 contiguous bytes/lane at B[n][kt+quad*8+kc*32]
//     (wave = 16 rows x one 64B line) -> load direct from L2-resident bf16 B,
//     prefetched one K-step ahead into named reg sets (unroll-2, static
//     indices). Removes B glds writes + B ds_reads (~half of LDS traffic).
//     A-path / sync structure / epilogue identical to R2, bit-identical math.

#define WS 8
#define MM 8192
#define KK 512
#define NN 1024
#define KTOT (WS * KK)  // 4096
#define BM 128
#define BN 128
#define BK 64
#define NBLK ((MM / BM) * (NN / BN))  // 512, divisible by 8

#define A_ELEMS ((size_t)WS * MM * KK)  // 33,554,432
#define B_ELEMS ((size_t)WS * NN * KK)  //  4,194,304
#define WS_NEEDED ((A_ELEMS + B_ELEMS) * 2)  // 75,497,472 bytes

typedef __attribute__((ext_vector_type(8))) short short8;
typedef __attribute__((ext_vector_type(4))) short short4v;
typedef __attribute__((ext_vector_type(4))) float floatx4;

static __device__ inline short f2bf(float f) {
    union { __hip_bfloat16 h; short s; } u;
    u.h = __float2bfloat16(f);  // RNE
    return u.s;
}

static __device__ inline void glds16(const short* g, short* l) {
    __builtin_amdgcn_global_load_lds(
        (const __attribute__((address_space(1))) unsigned int*)(uintptr_t)g,
        (__attribute__((address_space(3))) unsigned int*)(uintptr_t)l,
        16, 0, 0);
}

// ---------------- Phase 1: f32 -> bf16 convert (streaming) ----------------
#define CVT_ABLOCKS 16384
#define CVT_NBLOCKS 18432

__global__ __launch_bounds__(256)
void cvt_f32_bf16(const float* __restrict__ A, const float* __restrict__ B,
                  short* __restrict__ Abf, short* __restrict__ Bbf) {
    const float* src;
    short* dst;
    size_t base;
    if (blockIdx.x < CVT_ABLOCKS) {
        src = A; dst = Abf;
        base = ((size_t)blockIdx.x * 256 + threadIdx.x) * 8;
    } else {
        src = B; dst = Bbf;
        base = ((size_t)(blockIdx.x - CVT_ABLOCKS) * 256 + threadIdx.x) * 8;
    }
    float4 v0 = *(const float4*)(src + base);
    float4 v1 = *(const float4*)(src + base + 4);
    short8 o = { f2bf(v0.x), f2bf(v0.y), f2bf(v0.z), f2bf(v0.w),
                 f2bf(v1.x), f2bf(v1.y), f2bf(v1.z), f2bf(v1.w) };
    *(short8*)(dst + base) = o;
}

// ---------------- Phase 2: bf16 GEMM 128x128, B direct-to-reg -------------
// 4 waves: wr in {0,1} (64 rows), wc in {0,1} (64 cols); 4x4 frags/wave,
// 32 MFMA/wave/K-step. LDS = A only: 2 x 16 KB.
__global__ __launch_bounds__(256, 2)
void gemm_bf16_rs(const short* __restrict__ Abf, const short* __restrict__ Bbf,
                  float* __restrict__ C) {
    __shared__ short As[2][BM * BK];  // 32 KB total

    const int tid  = threadIdx.x;
    const int lane = tid & 63;
    const int wid  = tid >> 6;

    // Bijective XCD swizzle: XCD j owns 64 consecutive tiles = 8 contiguous
    // M-panel rows.
    const int lin = blockIdx.y * gridDim.x + blockIdx.x;       // 0..511
    const int T   = (lin & 7) * (NBLK / 8) + (lin >> 3);       // bijective
    const int ty  = T >> 3;          // 0..63  (M tile)
    const int tx  = T & 7;           // 0..7   (N tile)
    const int m0  = ty * BM;
    const int n0  = tx * BN;

    const int wr = wid >> 1, wc = wid & 1;
    const int lm = lane & 15, quad = lane >> 4;

    // A staging geometry (unchanged from R2): chunk = 64 lanes x 16B =
    // 8 rows x 8 segs; stored seg p of row r holds logical seg p^(r&7).
    const int lrow = lane >> 3;
    const int ss   = (lane & 7) ^ lrow;

    size_t gA[4];
#pragma unroll
    for (int t = 0; t < 4; ++t)
        gA[t] = (size_t)(m0 + wid * 32 + t * 8 + lrow) * KK + ss * 8;

    // B direct-frag element offsets within one rank bank: lane holds
    // B[n0 + wc*64 + j*16 + lm][k = kk + kc*32 + quad*8 .. +7] (16B contig).
    size_t gB[4];
#pragma unroll
    for (int j = 0; j < 4; ++j)
        gB[j] = (size_t)(n0 + wc * 64 + j * 16 + lm) * KK + quad * 8;

    floatx4 acc[4][4];
#pragma unroll
    for (int i = 0; i < 4; ++i)
#pragma unroll
        for (int j = 0; j < 4; ++j) acc[i][j] = (floatx4)0.f;

    auto stageA = [&](int buf, int kt) {
        const int w  = kt >> 9;         // rank bank (uniform)
        const int kk = kt & (KK - 1);   // offset inside bank (uniform)
        const short* Aw = Abf + (size_t)w * MM * KK + kk;
#pragma unroll
        for (int t = 0; t < 4; ++t)
            glds16(Aw + gA[t], &As[buf][(wid * 4 + t) * 512 + lane * 8]);
    };
    auto loadB = [&](short8 (&pre)[2][4], int kt) {
        const int w  = kt >> 9;
        const int kk = kt & (KK - 1);
        const short* Bw = Bbf + (size_t)w * NN * KK + kk;
#pragma unroll
        for (int kc = 0; kc < 2; ++kc)
#pragma unroll
            for (int j = 0; j < 4; ++j)
                pre[kc][j] = *(const short8*)(Bw + gB[j] + kc * 32);
    };

    // One K-step. `use` was prefetched last iter (completed at the prior
    // barrier's vmcnt(0) drain -> already in regs, no wait before MFMA).
    auto iter = [&](int kt, int cur, short8 (&use)[2][4], short8 (&pre)[2][4]) {
        if (kt + BK < KTOT) {
            stageA(cur ^ 1, kt + BK);   // glds: no dest regs, can't sink
            loadB(pre, kt + BK);        // reg prefetch for next step
        }
        short8 af[2][4];
#pragma unroll
        for (int kc = 0; kc < 2; ++kc)
#pragma unroll
            for (int i = 0; i < 4; ++i) {
                const int row = wr * 64 + i * 16 + lm;
                const int sa  = (kc * 4 + quad) ^ (lm & 7);
                af[kc][i] = *(const short8*)&As[cur][row * BK + sa * 8];
            }
        __builtin_amdgcn_s_setprio(1);
#pragma unroll
        for (int kc = 0; kc < 2; ++kc)
#pragma unroll
            for (int i = 0; i < 4; ++i)
#pragma unroll
                for (int j = 0; j < 4; ++j)
                    acc[i][j] = __builtin_amdgcn_mfma_f32_16x16x32_bf16(
                        af[kc][i], use[kc][j], acc[i][j], 0, 0, 0);
        __builtin_amdgcn_s_setprio(0);
        // Keep-alive: pin the prefetched frags into regs BEFORE the barrier
        // (prevents R3-style load-sinking past it; the wait it implies is
        // the barrier's own vmcnt(0) drain -> zero added cost).
        if (kt + BK < KTOT) {
#pragma unroll
            for (int kc = 0; kc < 2; ++kc)
#pragma unroll
                for (int j = 0; j < 4; ++j)
                    asm volatile("" : "+v"(pre[kc][j]));
        }
        __syncthreads();  // drains vmcnt (A staged, B frags landed) + lgkm
    };

    short8 bA[2][4], bB[2][4];
    loadB(bA, 0);
    stageA(0, 0);
    __syncthreads();

    for (int kt = 0; kt < KTOT; kt += 2 * BK) {
        iter(kt,      0, bA, bB);
        iter(kt + BK, 1, bB, bA);
    }

    // Epilogue: C/D layout col = lane&15 (n), row = quad*4 + r (m) [m89]
#pragma unroll
    for (int i = 0; i < 4; ++i)
#pragma unroll
        for (int j = 0; j < 4; ++j) {
            const int n = n0 + wc * 64 + j * 16 + lm;
#pragma unroll
            for (int r = 0; r < 4; ++r) {
                const int m = m0 + wr * 64 + i * 16 + quad * 4 + r;
                C[(size_t)m * NN + n] = acc[i][j][r];
            }
        }
}

// ---------------- Fallback (ws too small): f32-input fused kernel ----------
__global__ __launch_bounds__(256, 2)
void gemm_rs_fused(const float* __restrict__ A, const float* __restrict__ B,
                   float* __restrict__ C) {
    __shared__ short As[128 * 32];
    __shared__ short Bs[128 * 32];
    const int tid = threadIdx.x;
    const int m0 = blockIdx.y * 128;
    const int n0 = blockIdx.x * 128;
    const int wid = tid >> 6, lane = tid & 63;
    const int wr = wid >> 1, wc = wid & 1;
    const int lm = lane & 15, quad = lane >> 4;
    floatx4 acc[4][4];
#pragma unroll
    for (int i = 0; i < 4; ++i)
#pragma unroll
        for (int j = 0; j < 4; ++j) acc[i][j] = (floatx4)0.f;
    for (int kt = 0; kt < KTOT; kt += 32) {
        const int w = kt >> 9, kk = kt & (KK - 1);
        const float* Aw = A + (size_t)w * MM * KK;
        const float* Bw = B + (size_t)w * NN * KK;
        __syncthreads();
#pragma unroll
        for (int i = 0; i < 4; ++i) {
            const int idx = i * 256 + tid;
            const int row = idx >> 3;
            const int c4 = (idx & 7) * 4;
            float4 av = *(const float4*)&Aw[(size_t)(m0 + row) * KK + kk + c4];
            float4 bv = *(const float4*)&Bw[(size_t)(n0 + row) * KK + kk + c4];
            short4v a4 = { f2bf(av.x), f2bf(av.y), f2bf(av.z), f2bf(av.w) };
            short4v b4 = { f2bf(bv.x), f2bf(bv.y), f2bf(bv.z), f2bf(bv.w) };
            *(short4v*)&As[row * 32 + c4] = a4;
            *(short4v*)&Bs[row * 32 + c4] = b4;
        }
        __syncthreads();
        short8 af[4], bfr[4];
#pragma unroll
        for (int i = 0; i < 4; ++i)
            af[i] = *(const short8*)&As[(wr * 64 + i * 16 + lm) * 32 + quad * 8];
#pragma unroll
        for (int j = 0; j < 4; ++j)
            bfr[j] = *(const short8*)&Bs[(wc * 64 + j * 16 + lm) * 32 + quad * 8];
#pragma unroll
        for (int i = 0; i < 4; ++i)
#pragma unroll
            for (int j = 0; j < 4; ++j)
                acc[i][j] = __builtin_amdgcn_mfma_f32_16x16x32_bf16(
                    af[i], bfr[j], acc[i][j], 0, 0, 0);
    }
#pragma unroll
    for (int i = 0; i < 4; ++i)
#pragma unroll
        for (int j = 0; j < 4; ++j) {
            const int n = n0 + wc * 64 + j * 16 + lm;
#pragma unroll
            for (int r = 0; r < 4; ++r) {
                const int m = m0 + wr * 64 + i * 16 + quad * 4 + r;
                C[(size_t)m * NN + n] = acc[i][j][r];
            }
        }
}

extern "C" void kernel_launch(void* const* d_in, const int* in_sizes, int n_in,
                              void* d_out, int out_size, void* d_ws, size_t ws_size,
                              hipStream_t stream) {
    const float* A = (const float*)d_in[0];  // [8,8192,512]
    const float* B = (const float*)d_in[1];  // [8,1024,512]
    float* C = (float*)d_out;                // [8192,1024]

    if (ws_size >= WS_NEEDED) {
        short* Abf = (short*)d_ws;
        short* Bbf = Abf + A_ELEMS;
        cvt_f32_bf16<<<CVT_NBLOCKS, 256, 0, stream>>>(A, B, Abf, Bbf);
        dim3 grid(NN / BN, MM / BM);  // (8, 64) = 512 blocks
        gemm_bf16_rs<<<grid, 256, 0, stream>>>(Abf, Bbf, C);
    } else {
        dim3 grid(NN / 128, MM / 128);  // (8, 64)
        gemm_rs_fused<<<grid, 256, 0, stream>>>(A, B, C);
    }
}

// Round 5
// 285.727 us; speedup vs baseline: 1.2141x; 1.2141x over previous
//
#include <hip/hip_runtime.h>
#include <hip/hip_bf16.h>

// GemmRS: out[m,n] = sum_{w,k} A[w,m,k]*B[w,n,k]
// A: [8,8192,512] f32, B: [8,1024,512] f32, out: [8192,1024] f32.
//
// R1: dbuf LDS (1 barrier/K-step), bijective XCD swizzle, setprio.
// R2: 128x128 tile, 4 waves -> cvt ~38us + gemm ~63us. gemm is exactly at
//     the LDS byte wall: (8.39 MB reads + 4.19 MB writes)/CU at ~85 B/cyc
//     = 61.8us ~= measured 63.
// R3: fused f32 reg-staging FAILED (169us) - compiler won't hold staging
//     regs across barriers.
// R4: B-direct-to-reg prefetch FAILED (146us) - same failure class
//     (VGPR=104: prefetch set not kept live; loads serialized).
//     LESSON: glds-only staging; never fight the register allocator.
// R5: keep R2's exact glds/dbuf/swizzle structure; change ONLY the wave
//     decomposition: 2 waves/block (128 thr), per-wave tile 128x64
//     (was 64x64). Frag-read bytes/FLOP drop 25% (ratio 32->42.7);
//     LDS total 12.6->10.5 MB/CU -> predicted gemm ~52us.

#define WS 8
#define MM 8192
#define KK 512
#define NN 1024
#define KTOT (WS * KK)  // 4096
#define BM 128
#define BN 128
#define BK 64
#define NBLK ((MM / BM) * (NN / BN))  // 512, divisible by 8

#define A_ELEMS ((size_t)WS * MM * KK)  // 33,554,432
#define B_ELEMS ((size_t)WS * NN * KK)  //  4,194,304
#define WS_NEEDED ((A_ELEMS + B_ELEMS) * 2)  // 75,497,472 bytes

typedef __attribute__((ext_vector_type(8))) short short8;
typedef __attribute__((ext_vector_type(4))) short short4v;
typedef __attribute__((ext_vector_type(4))) float floatx4;

static __device__ inline short f2bf(float f) {
    union { __hip_bfloat16 h; short s; } u;
    u.h = __float2bfloat16(f);  // RNE
    return u.s;
}

static __device__ inline void glds16(const short* g, short* l) {
    __builtin_amdgcn_global_load_lds(
        (const __attribute__((address_space(1))) unsigned int*)(uintptr_t)g,
        (__attribute__((address_space(3))) unsigned int*)(uintptr_t)l,
        16, 0, 0);
}

// ---------------- Phase 1: f32 -> bf16 convert (streaming) ----------------
#define CVT_ABLOCKS 16384
#define CVT_NBLOCKS 18432

__global__ __launch_bounds__(256)
void cvt_f32_bf16(const float* __restrict__ A, const float* __restrict__ B,
                  short* __restrict__ Abf, short* __restrict__ Bbf) {
    const float* src;
    short* dst;
    size_t base;
    if (blockIdx.x < CVT_ABLOCKS) {
        src = A; dst = Abf;
        base = ((size_t)blockIdx.x * 256 + threadIdx.x) * 8;
    } else {
        src = B; dst = Bbf;
        base = ((size_t)(blockIdx.x - CVT_ABLOCKS) * 256 + threadIdx.x) * 8;
    }
    float4 v0 = *(const float4*)(src + base);
    float4 v1 = *(const float4*)(src + base + 4);
    short8 o = { f2bf(v0.x), f2bf(v0.y), f2bf(v0.z), f2bf(v0.w),
                 f2bf(v1.x), f2bf(v1.y), f2bf(v1.z), f2bf(v1.w) };
    *(short8*)(dst + base) = o;
}

// ---------------- Phase 2: bf16 GEMM 128x128, 2 waves, 128x64/wave --------
// Wave wid owns rows 0..127 x cols wid*64..wid*64+63.
// Per wave per K-step: 8 m-frags x 4 n-frags x 2 kc = 64 MFMA.
__global__ __launch_bounds__(128, 1)
void gemm_bf16_rs(const short* __restrict__ Abf, const short* __restrict__ Bbf,
                  float* __restrict__ C) {
    __shared__ short As[2][BM * BK];  // 32 KB
    __shared__ short Bs[2][BN * BK];  // 32 KB

    const int tid  = threadIdx.x;
    const int lane = tid & 63;
    const int wid  = tid >> 6;       // 0..1

    // Bijective XCD swizzle: XCD j owns 64 consecutive tiles = 8 contiguous
    // M-panel rows.
    const int lin = blockIdx.y * gridDim.x + blockIdx.x;       // 0..511
    const int T   = (lin & 7) * (NBLK / 8) + (lin >> 3);       // bijective
    const int ty  = T >> 3;          // 0..63  (M tile)
    const int tx  = T & 7;           // 0..7   (N tile)
    const int m0  = ty * BM;
    const int n0  = tx * BN;

    const int lm = lane & 15, quad = lane >> 4;

    // Staging geometry (R2-identical): chunk = 64 lanes x 16B = 8 rows x
    // 8 segs (seg = 8 bf16). Stored seg p of row r holds logical seg
    // p ^ (r&7); frag reads compensate with the same XOR.
    const int lrow = lane >> 3;
    const int ss   = (lane & 7) ^ lrow;

    // Each wave stages 8 A-chunks + 8 B-chunks (rows wid*64 .. wid*64+63).
    size_t gA[8], gB[8];
#pragma unroll
    for (int t = 0; t < 8; ++t) {
        gA[t] = (size_t)(m0 + wid * 64 + t * 8 + lrow) * KK + ss * 8;
        gB[t] = (size_t)(n0 + wid * 64 + t * 8 + lrow) * KK + ss * 8;
    }

    floatx4 acc[8][4];
#pragma unroll
    for (int i = 0; i < 8; ++i)
#pragma unroll
        for (int j = 0; j < 4; ++j) acc[i][j] = (floatx4)0.f;

    auto stage = [&](int buf, int kt) {
        const int w  = kt >> 9;         // rank bank (uniform)
        const int kk = kt & (KK - 1);   // offset inside bank (uniform)
        const short* Aw = Abf + (size_t)w * MM * KK + kk;
        const short* Bw = Bbf + (size_t)w * NN * KK + kk;
#pragma unroll
        for (int t = 0; t < 8; ++t)
            glds16(Aw + gA[t], &As[buf][(wid * 8 + t) * 512 + lane * 8]);
#pragma unroll
        for (int t = 0; t < 8; ++t)
            glds16(Bw + gB[t], &Bs[buf][(wid * 8 + t) * 512 + lane * 8]);
    };

    // Prologue: stage tile 0; barrier's vmcnt(0) drain makes it ready.
    stage(0, 0);
    __syncthreads();

    for (int kt = 0; kt < KTOT; kt += BK) {
        const int cur = (kt >> 6) & 1;
        // Issue next tile's staging FIRST (glds has no dest regs: the
        // compiler cannot sink or spill it). Latency hides under the
        // ds_read + 64-MFMA cluster below; single end-of-iter barrier.
        if (kt + BK < KTOT) stage(cur ^ 1, kt + BK);

        short8 af[2][8], bfr[2][4];
#pragma unroll
        for (int kc = 0; kc < 2; ++kc) {
#pragma unroll
            for (int i = 0; i < 8; ++i) {
                const int row = i * 16 + lm;                 // all 128 rows
                const int sa  = (kc * 4 + quad) ^ (lm & 7);
                af[kc][i] = *(const short8*)&As[cur][row * BK + sa * 8];
            }
#pragma unroll
            for (int j = 0; j < 4; ++j) {
                const int row = wid * 64 + j * 16 + lm;      // wave's 64 cols
                const int sb  = (kc * 4 + quad) ^ (lm & 7);
                bfr[kc][j] = *(const short8*)&Bs[cur][row * BK + sb * 8];
            }
        }
        __builtin_amdgcn_s_setprio(1);
#pragma unroll
        for (int kc = 0; kc < 2; ++kc)
#pragma unroll
            for (int i = 0; i < 8; ++i)
#pragma unroll
                for (int j = 0; j < 4; ++j)
                    acc[i][j] = __builtin_amdgcn_mfma_f32_16x16x32_bf16(
                        af[kc][i], bfr[kc][j], acc[i][j], 0, 0, 0);
        __builtin_amdgcn_s_setprio(0);
        __syncthreads();  // drains vmcnt (next tile staged) + lgkm
    }

    // Epilogue: C/D layout col = lane&15 (n), row = quad*4 + r (m) [m89]
#pragma unroll
    for (int i = 0; i < 8; ++i)
#pragma unroll
        for (int j = 0; j < 4; ++j) {
            const int n = n0 + wid * 64 + j * 16 + lm;
#pragma unroll
            for (int r = 0; r < 4; ++r) {
                const int m = m0 + i * 16 + quad * 4 + r;
                C[(size_t)m * NN + n] = acc[i][j][r];
            }
        }
}

// ---------------- Fallback (ws too small): f32-input fused kernel ----------
__global__ __launch_bounds__(256, 2)
void gemm_rs_fused(const float* __restrict__ A, const float* __restrict__ B,
                   float* __restrict__ C) {
    __shared__ short As[128 * 32];
    __shared__ short Bs[128 * 32];
    const int tid = threadIdx.x;
    const int m0 = blockIdx.y * 128;
    const int n0 = blockIdx.x * 128;
    const int wid = tid >> 6, lane = tid & 63;
    const int wr = wid >> 1, wc = wid & 1;
    const int lm = lane & 15, quad = lane >> 4;
    floatx4 acc[4][4];
#pragma unroll
    for (int i = 0; i < 4; ++i)
#pragma unroll
        for (int j = 0; j < 4; ++j) acc[i][j] = (floatx4)0.f;
    for (int kt = 0; kt < KTOT; kt += 32) {
        const int w = kt >> 9, kk = kt & (KK - 1);
        const float* Aw = A + (size_t)w * MM * KK;
        const float* Bw = B + (size_t)w * NN * KK;
        __syncthreads();
#pragma unroll
        for (int i = 0; i < 4; ++i) {
            const int idx = i * 256 + tid;
            const int row = idx >> 3;
            const int c4 = (idx & 7) * 4;
            float4 av = *(const float4*)&Aw[(size_t)(m0 + row) * KK + kk + c4];
            float4 bv = *(const float4*)&Bw[(size_t)(n0 + row) * KK + kk + c4];
            short4v a4 = { f2bf(av.x), f2bf(av.y), f2bf(av.z), f2bf(av.w) };
            short4v b4 = { f2bf(bv.x), f2bf(bv.y), f2bf(bv.z), f2bf(bv.w) };
            *(short4v*)&As[row * 32 + c4] = a4;
            *(short4v*)&Bs[row * 32 + c4] = b4;
        }
        __syncthreads();
        short8 af[4], bfr[4];
#pragma unroll
        for (int i = 0; i < 4; ++i)
            af[i] = *(const short8*)&As[(wr * 64 + i * 16 + lm) * 32 + quad * 8];
#pragma unroll
        for (int j = 0; j < 4; ++j)
            bfr[j] = *(const short8*)&Bs[(wc * 64 + j * 16 + lm) * 32 + quad * 8];
#pragma unroll
        for (int i = 0; i < 4; ++i)
#pragma unroll
            for (int j = 0; j < 4; ++j)
                acc[i][j] = __builtin_amdgcn_mfma_f32_16x16x32_bf16(
                    af[i], bfr[j], acc[i][j], 0, 0, 0);
    }
#pragma unroll
    for (int i = 0; i < 4; ++i)
#pragma unroll
        for (int j = 0; j < 4; ++j) {
            const int n = n0 + wc * 64 + j * 16 + lm;
#pragma unroll
            for (int r = 0; r < 4; ++r) {
                const int m = m0 + wr * 64 + i * 16 + quad * 4 + r;
                C[(size_t)m * NN + n] = acc[i][j][r];
            }
        }
}

extern "C" void kernel_launch(void* const* d_in, const int* in_sizes, int n_in,
                              void* d_out, int out_size, void* d_ws, size_t ws_size,
                              hipStream_t stream) {
    const float* A = (const float*)d_in[0];  // [8,8192,512]
    const float* B = (const float*)d_in[1];  // [8,1024,512]
    float* C = (float*)d_out;                // [8192,1024]

    if (ws_size >= WS_NEEDED) {
        short* Abf = (short*)d_ws;
        short* Bbf = Abf + A_ELEMS;
        cvt_f32_bf16<<<CVT_NBLOCKS, 256, 0, stream>>>(A, B, Abf, Bbf);
        dim3 grid(NN / BN, MM / BM);  // (8, 64) = 512 blocks
        gemm_bf16_rs<<<grid, 128, 0, stream>>>(Abf, Bbf, C);
    } else {
        dim3 grid(NN / 128, MM / 128);  // (8, 64)
        gemm_rs_fused<<<grid, 256, 0, stream>>>(A, B, C);
    }
}